// Round 10
// baseline (73.206 us; speedup 1.0000x reference)
//
#include <hip/hip_runtime.h>

// Problem constants (fixed by setup_inputs in the reference)
constexpr int B = 8, C = 64, H = 64, W = 64;
constexpr int N = 512;          // rois per leading dim
constexpr int R = N * B;        // 4096 total ROIs
constexpr int HW = H * W;

// Antiderivative of tent kernel max(0, 1-|t|), clipped to [-1, 1].
__device__ __forceinline__ float tent_int(float t) {
    t = fminf(1.0f, fmaxf(-1.0f, t));
    float u = t + 1.0f;
    float v = 1.0f - t;
    return (t < 0.0f) ? 0.5f * u * u : 1.0f - 0.5f * v * v;
}

__device__ __forceinline__ float bf_lo(unsigned int u) {    // low short -> f32
    union { unsigned int i; float f; } c; c.i = u << 16; return c.f;
}
__device__ __forceinline__ float bf_hi(unsigned int u) {    // high short -> f32
    union { unsigned int i; float f; } c; c.i = u & 0xFFFF0000u; return c.f;
}
__device__ __forceinline__ unsigned short f2bf(float x) {   // round-to-nearest-even
    union { float f; unsigned int i; } c; c.f = x;
    unsigned int r = c.i + 0x7FFFu + ((c.i >> 16) & 1u);
    return (unsigned short)(r >> 16);
}

// ---------------------------------------------------------------------------
// Kernel 1: transpose [B, C, HW] fp32 -> [B, HW, C] bf16 (channel innermost).
// Instruction-lean rebuild: float4 global loads (4/thread), b128 LDS writes
// into [64][68] fp32 tile (16B-aligned, balanced banks), read-back 4x4 scalar
// reads (2-way bank alias = free) -> pack -> ushort4 stores (4/thread).
// ~60 instrs/thread vs ~130 in the previous scalar version.
// ---------------------------------------------------------------------------
__global__ __launch_bounds__(256) void transpose_kernel(
    const float* __restrict__ in,          // [B, C, HW] fp32
    unsigned short* __restrict__ out)      // [B, HW, C] bf16
{
    __shared__ float tile[64][68];           // pad 68: b128-aligned rows
    const int b  = blockIdx.x >> 6;          // 0..7
    const int tp = (blockIdx.x & 63) * 64;   // pixel tile start
    const int t  = threadIdx.x;

    // Load: thread covers (c = (t>>4) + 16s, px4 = 4*(t&15)); 256B contiguous
    // per 16-lane group.
    {
        const float* src = in + (size_t)b * C * HW + tp;
        const int c0  = t >> 4;              // 0..15
        const int px4 = (t & 15) * 4;
        #pragma unroll
        for (int s = 0; s < 4; ++s) {
            const int c = c0 + 16 * s;
            const float4 v = *reinterpret_cast<const float4*>(src + (size_t)c * HW + px4);
            *reinterpret_cast<float4*>(&tile[c][px4]) = v;
        }
    }
    __syncthreads();

    // Store: thread covers (p = t>>2, cq = (t&3) + 4s); ushort4 = 4 channels.
    {
        unsigned short* dst = out + ((size_t)b * HW + tp) * C;
        const int p  = t >> 2;               // 0..63
        const int q0 = t & 3;
        #pragma unroll
        for (int s = 0; s < 4; ++s) {
            const int c = (q0 + 4 * s) * 4;  // channel base 0..60
            ushort4 u;
            u.x = f2bf(tile[c    ][p]);
            u.y = f2bf(tile[c + 1][p]);
            u.z = f2bf(tile[c + 2][p]);
            u.w = f2bf(tile[c + 3][p]);
            *reinterpret_cast<ushort4*>(dst + (size_t)p * C + c) = u;
        }
    }
}

// ---------------------------------------------------------------------------
// Kernel 2: main PrRoIPool (telescoped). ONE WAVE PER ROI -- no LDS, no
// __syncthreads. Grid = 4096 x 64.
// Lane decomposition: pg = lane>>3 (8 adjacent pixels), cg = lane&7
// (8-channel bf16 group, uint4 = 16B/lane). One wave-load = 1KB contiguous.
// NEW: second column chunk issued only when nx > 8 (wave-uniform branch) --
// when nx <= 8 (~25% of ROIs) chunk 2 is entirely zero-weighted, skip it.
// ---------------------------------------------------------------------------
__global__ __launch_bounds__(64) void prroi_main(
    const unsigned short* __restrict__ ft, // [B, HW, C] bf16
    const float* __restrict__ rois,        // [N, B, 1, 1, 5]
    float* __restrict__ out)               // [R, C]
{
    const int r    = blockIdx.x;
    const int lane = threadIdx.x & 63;
    const int pg   = lane >> 3;          // pixel subgroup 0..7
    const int cg   = lane & 7;           // channel group (8 channels)

    const int bo = r >> 9;               // r / N (N=512)
    const int n  = r & 511;
    const float* rp = rois + ((size_t)n * B + bo) * 5;

    const int   b  = (int)rp[0];
    const float x1 = rp[1], y1 = rp[2], x2 = rp[3], y2 = rp[4];

    const int i_lo = max(0, (int)ceilf(y1 - 1.0f));
    const int i_hi = min(H - 1, (int)floorf(y2 + 1.0f));
    const int j_lo = max(0, (int)ceilf(x1 - 1.0f));
    const int j_hi = min(W - 1, (int)floorf(x2 + 1.0f));
    const int ny = i_hi - i_lo + 1;      // <= 15
    const int nx = j_hi - j_lo + 1;      // <= 15
    const bool two = (nx > 8);           // wave-uniform: need 2nd column chunk?

    // Per-lane column weight + element offset (clamped addr, 0 weight OOB).
    float wx[2];
    int   coff[2];
    #pragma unroll
    for (int k = 0; k < 2; ++k) {
        const int  jj    = k * 8 + pg;
        const int  j     = j_lo + jj;
        const bool valid = (jj < nx);
        const float jf   = (float)j;
        wx[k]   = valid ? (tent_int(x2 - jf) - tent_int(x1 - jf)) : 0.0f;
        coff[k] = min(j, W - 1) * C + cg * 8;     // element (short) offset
    }

    float acc[8] = {0.f, 0.f, 0.f, 0.f, 0.f, 0.f, 0.f, 0.f};
    const unsigned short* fb = ft + ((size_t)b * HW + (size_t)i_lo * W) * C;
    for (int ii = 0; ii < ny; ++ii) {
        const float fi = (float)(i_lo + ii);
        const float wy = tent_int(y2 - fi) - tent_int(y1 - fi);  // wave-uniform
        const unsigned short* rowp = fb + (size_t)ii * (W * C);

        const uint4 u0 = *reinterpret_cast<const uint4*>(rowp + coff[0]);
        const float w0 = wy * wx[0];
        acc[0] = fmaf(w0, bf_lo(u0.x), acc[0]);
        acc[1] = fmaf(w0, bf_hi(u0.x), acc[1]);
        acc[2] = fmaf(w0, bf_lo(u0.y), acc[2]);
        acc[3] = fmaf(w0, bf_hi(u0.y), acc[3]);
        acc[4] = fmaf(w0, bf_lo(u0.z), acc[4]);
        acc[5] = fmaf(w0, bf_hi(u0.z), acc[5]);
        acc[6] = fmaf(w0, bf_lo(u0.w), acc[6]);
        acc[7] = fmaf(w0, bf_hi(u0.w), acc[7]);

        if (two) {
            const uint4 u1 = *reinterpret_cast<const uint4*>(rowp + coff[1]);
            const float w1 = wy * wx[1];
            acc[0] = fmaf(w1, bf_lo(u1.x), acc[0]);
            acc[1] = fmaf(w1, bf_hi(u1.x), acc[1]);
            acc[2] = fmaf(w1, bf_lo(u1.y), acc[2]);
            acc[3] = fmaf(w1, bf_hi(u1.y), acc[3]);
            acc[4] = fmaf(w1, bf_lo(u1.z), acc[4]);
            acc[5] = fmaf(w1, bf_hi(u1.z), acc[5]);
            acc[6] = fmaf(w1, bf_lo(u1.w), acc[6]);
            acc[7] = fmaf(w1, bf_hi(u1.w), acc[7]);
        }
    }

    // Fold the 8 pixel subgroups (lane bits 3..5).
    #pragma unroll
    for (int e = 0; e < 8; ++e) {
        acc[e] += __shfl_xor(acc[e], 8);
        acc[e] += __shfl_xor(acc[e], 16);
        acc[e] += __shfl_xor(acc[e], 32);
    }

    // mean over 49 bins of integ/bin_area == acc / ((x2-x1)(y2-y1))
    const float prod  = (x2 - x1) * (y2 - y1);
    const float scale = (prod > 0.0f) ? (1.0f / fmaxf(prod, 49e-12f)) : 0.0f;

    // Lanes 0..7 each store 8 channels: 2x dwordx4, 256B contiguous total.
    if (lane < 8) {
        float* op = out + (size_t)r * C + lane * 8;
        float4 lo = make_float4(acc[0] * scale, acc[1] * scale,
                                acc[2] * scale, acc[3] * scale);
        float4 hi = make_float4(acc[4] * scale, acc[5] * scale,
                                acc[6] * scale, acc[7] * scale);
        *reinterpret_cast<float4*>(op)     = lo;
        *reinterpret_cast<float4*>(op + 4) = hi;
    }
}

// ---------------------------------------------------------------------------
// Fallback (round-1 kernel): used only if ws_size is too small.
// ---------------------------------------------------------------------------
__global__ __launch_bounds__(64) void prroi_fallback(
    const float* __restrict__ feature, const float* __restrict__ rois,
    float* __restrict__ out)
{
    const int r  = blockIdx.x;
    const int bo = r / N;
    const int n  = r - bo * N;
    const float* rp = rois + ((size_t)n * B + bo) * 5;
    const float x1 = rp[1], y1 = rp[2], x2 = rp[3], y2 = rp[4];
    const int b = (int)rp[0];
    int i_lo = max(0, (int)ceilf(y1 - 1.0f));
    int i_hi = min(H - 1, (int)floorf(y2 + 1.0f));
    int j_lo = max(0, (int)ceilf(x1 - 1.0f));
    int j_hi = min(W - 1, (int)floorf(x2 + 1.0f));
    const int ny = i_hi - i_lo + 1;
    const int nx = j_hi - j_lo + 1;
    __shared__ float sWy[16], sWx[16];
    const int t = threadIdx.x;
    if (t < 16) {
        int i = i_lo + t;
        sWy[t] = (t < ny) ? (tent_int(y2 - (float)i) - tent_int(y1 - (float)i)) : 0.0f;
    } else if (t < 32) {
        int tt = t - 16, j = j_lo + tt;
        sWx[tt] = (tt < nx) ? (tent_int(x2 - (float)j) - tent_int(x1 - (float)j)) : 0.0f;
    }
    __syncthreads();
    const float* fb = feature + ((size_t)b * C + t) * HW;
    float acc = 0.0f;
    for (int ii = 0; ii < ny; ++ii) {
        const float* row = fb + (size_t)(i_lo + ii) * W + j_lo;
        float rowsum = 0.0f;
        for (int jj = 0; jj < nx; ++jj) rowsum = fmaf(sWx[jj], row[jj], rowsum);
        acc = fmaf(sWy[ii], rowsum, acc);
    }
    const float bw = (x2 - x1) * (1.0f / 7.0f), bh = (y2 - y1) * (1.0f / 7.0f);
    const float area = fmaxf(bw * bh, 0.0f);
    out[(size_t)r * C + t] = (area > 0.0f) ? (acc / (49.0f * fmaxf(area, 1e-12f))) : 0.0f;
}

extern "C" void kernel_launch(void* const* d_in, const int* in_sizes, int n_in,
                              void* d_out, int out_size, void* d_ws, size_t ws_size,
                              hipStream_t stream) {
    const float* feature = (const float*)d_in[0];
    const float* rois    = (const float*)d_in[1];
    float* out           = (float*)d_out;

    const size_t need = (size_t)B * HW * C * sizeof(unsigned short);  // 4 MB
    if (ws_size >= need) {
        unsigned short* ft = (unsigned short*)d_ws;
        transpose_kernel<<<B * (HW / 64), 256, 0, stream>>>(feature, ft);
        prroi_main<<<R, 64, 0, stream>>>(ft, rois, out);
    } else {
        prroi_fallback<<<R, 64, 0, stream>>>(feature, rois, out);
    }
}

// Round 11
// 71.272 us; speedup vs baseline: 1.0271x; 1.0271x over previous
//
#include <hip/hip_runtime.h>

// Problem constants (fixed by setup_inputs in the reference)
constexpr int B = 8, C = 64, H = 64, W = 64;
constexpr int N = 512;          // rois per leading dim
constexpr int R = N * B;        // 4096 total ROIs
constexpr int HW = H * W;

// Antiderivative of tent kernel max(0, 1-|t|), clipped to [-1, 1].
__device__ __forceinline__ float tent_int(float t) {
    t = fminf(1.0f, fmaxf(-1.0f, t));
    float u = t + 1.0f;
    float v = 1.0f - t;
    return (t < 0.0f) ? 0.5f * u * u : 1.0f - 0.5f * v * v;
}

__device__ __forceinline__ float bf_lo(unsigned int u) {    // low short -> f32
    union { unsigned int i; float f; } c; c.i = u << 16; return c.f;
}
__device__ __forceinline__ float bf_hi(unsigned int u) {    // high short -> f32
    union { unsigned int i; float f; } c; c.i = u & 0xFFFF0000u; return c.f;
}
__device__ __forceinline__ unsigned short f2bf(float x) {   // round-to-nearest-even
    union { float f; unsigned int i; } c; c.f = x;
    unsigned int r = c.i + 0x7FFFu + ((c.i >> 16) & 1u);
    return (unsigned short)(r >> 16);
}

// ---------------------------------------------------------------------------
// Kernel 1: transpose [B, C, HW] fp32 -> [B, HW, C] bf16 (channel innermost).
// 512 blocks x 256 threads; 64x64 LDS tile with +1 pad. (R9 version — the
// R10 "lean" rebuild regressed: longer read-pack-store dependence chain.)
// ---------------------------------------------------------------------------
__global__ __launch_bounds__(256) void transpose_kernel(
    const float* __restrict__ in,          // [B, C, HW] fp32
    unsigned short* __restrict__ out)      // [B, HW, C] bf16
{
    __shared__ float tile[64][65];
    const int b  = blockIdx.x >> 6;          // 0..7
    const int tp = (blockIdx.x & 63) * 64;   // pixel tile start
    const int t  = threadIdx.x;
    const int tq = t >> 6;                   // 0..3 (wave id)
    const int tl = t & 63;                   // lane

    const float* src = in + (size_t)b * C * HW;
    #pragma unroll
    for (int s = 0; s < 16; ++s) {
        int c = s * 4 + tq;
        tile[c][tl] = src[(size_t)c * HW + tp + tl];   // coalesced 256B/wave
    }
    __syncthreads();
    unsigned short* dst = out + ((size_t)b * HW + tp) * C;
    #pragma unroll
    for (int s = 0; s < 16; ++s) {
        int p = s * 4 + tq;
        dst[(size_t)p * C + tl] = f2bf(tile[tl][p]);   // coalesced 128B/wave
    }
}

// ---------------------------------------------------------------------------
// Kernel 2: main PrRoIPool (telescoped). ONE WAVE PER ROI -- no LDS, no
// __syncthreads, no inter-wave reduce. Grid = 4096 x 64. (R9 version — the
// R10 wave-uniform chunk-skip branch regressed.)
// Lane decomposition: pg = lane>>3 (8 adjacent pixels), cg = lane&7
// (8-channel bf16 group, uint4 = 16B/lane). One wave-load = 1KB contiguous.
// Wave walks all window rows (ny <= 15, nk <= 2 chunks each); 3-step shfl
// fold over pg; 8 lanes store 2x dwordx4 (256B contiguous).
// ---------------------------------------------------------------------------
__global__ __launch_bounds__(64) void prroi_main(
    const unsigned short* __restrict__ ft, // [B, HW, C] bf16
    const float* __restrict__ rois,        // [N, B, 1, 1, 5]
    float* __restrict__ out)               // [R, C]
{
    const int r    = blockIdx.x;
    const int lane = threadIdx.x & 63;
    const int pg   = lane >> 3;          // pixel subgroup 0..7
    const int cg   = lane & 7;           // channel group (8 channels)

    const int bo = r >> 9;               // r / N (N=512)
    const int n  = r & 511;
    const float* rp = rois + ((size_t)n * B + bo) * 5;

    const int   b  = (int)rp[0];
    const float x1 = rp[1], y1 = rp[2], x2 = rp[3], y2 = rp[4];

    const int i_lo = max(0, (int)ceilf(y1 - 1.0f));
    const int i_hi = min(H - 1, (int)floorf(y2 + 1.0f));
    const int j_lo = max(0, (int)ceilf(x1 - 1.0f));
    const int j_hi = min(W - 1, (int)floorf(x2 + 1.0f));
    const int ny = i_hi - i_lo + 1;      // <= 15
    const int nx = j_hi - j_lo + 1;      // <= 15
    const int nk = (nx + 7) >> 3;        // 8-pixel column chunks (1 or 2)

    // Per-lane column weight + element offset (clamped addr, 0 weight OOB).
    float wx[2];
    int   coff[2];
    #pragma unroll
    for (int k = 0; k < 2; ++k) {
        const int  jj    = k * 8 + pg;
        const int  j     = j_lo + jj;
        const bool valid = (jj < nx);
        const float jf   = (float)j;
        wx[k]   = valid ? (tent_int(x2 - jf) - tent_int(x1 - jf)) : 0.0f;
        coff[k] = min(j, W - 1) * C + cg * 8;     // element (short) offset
    }

    float acc[8] = {0.f, 0.f, 0.f, 0.f, 0.f, 0.f, 0.f, 0.f};
    const unsigned short* fb = ft + ((size_t)b * HW + (size_t)i_lo * W) * C;
    for (int ii = 0; ii < ny; ++ii) {
        const float fi = (float)(i_lo + ii);
        const float wy = tent_int(y2 - fi) - tent_int(y1 - fi);  // wave-uniform
        const unsigned short* rowp = fb + (size_t)ii * (W * C);
        #pragma unroll 2
        for (int k = 0; k < nk; ++k) {
            const uint4 u = *reinterpret_cast<const uint4*>(rowp + coff[k]);
            const float w = wy * wx[k];
            acc[0] = fmaf(w, bf_lo(u.x), acc[0]);
            acc[1] = fmaf(w, bf_hi(u.x), acc[1]);
            acc[2] = fmaf(w, bf_lo(u.y), acc[2]);
            acc[3] = fmaf(w, bf_hi(u.y), acc[3]);
            acc[4] = fmaf(w, bf_lo(u.z), acc[4]);
            acc[5] = fmaf(w, bf_hi(u.z), acc[5]);
            acc[6] = fmaf(w, bf_lo(u.w), acc[6]);
            acc[7] = fmaf(w, bf_hi(u.w), acc[7]);
        }
    }

    // Fold the 8 pixel subgroups (lane bits 3..5).
    #pragma unroll
    for (int e = 0; e < 8; ++e) {
        acc[e] += __shfl_xor(acc[e], 8);
        acc[e] += __shfl_xor(acc[e], 16);
        acc[e] += __shfl_xor(acc[e], 32);
    }

    // mean over 49 bins of integ/bin_area == acc / ((x2-x1)(y2-y1))
    const float prod  = (x2 - x1) * (y2 - y1);
    const float scale = (prod > 0.0f) ? (1.0f / fmaxf(prod, 49e-12f)) : 0.0f;

    // Lanes 0..7 (pg==0, cg==lane) each store 8 channels: 2x dwordx4,
    // 256B contiguous across the 8 lanes.
    if (lane < 8) {
        float* op = out + (size_t)r * C + lane * 8;
        float4 lo = make_float4(acc[0] * scale, acc[1] * scale,
                                acc[2] * scale, acc[3] * scale);
        float4 hi = make_float4(acc[4] * scale, acc[5] * scale,
                                acc[6] * scale, acc[7] * scale);
        *reinterpret_cast<float4*>(op)     = lo;
        *reinterpret_cast<float4*>(op + 4) = hi;
    }
}

// ---------------------------------------------------------------------------
// Fallback (round-1 kernel): used only if ws_size is too small.
// ---------------------------------------------------------------------------
__global__ __launch_bounds__(64) void prroi_fallback(
    const float* __restrict__ feature, const float* __restrict__ rois,
    float* __restrict__ out)
{
    const int r  = blockIdx.x;
    const int bo = r / N;
    const int n  = r - bo * N;
    const float* rp = rois + ((size_t)n * B + bo) * 5;
    const float x1 = rp[1], y1 = rp[2], x2 = rp[3], y2 = rp[4];
    const int b = (int)rp[0];
    int i_lo = max(0, (int)ceilf(y1 - 1.0f));
    int i_hi = min(H - 1, (int)floorf(y2 + 1.0f));
    int j_lo = max(0, (int)ceilf(x1 - 1.0f));
    int j_hi = min(W - 1, (int)floorf(x2 + 1.0f));
    const int ny = i_hi - i_lo + 1;
    const int nx = j_hi - j_lo + 1;
    __shared__ float sWy[16], sWx[16];
    const int t = threadIdx.x;
    if (t < 16) {
        int i = i_lo + t;
        sWy[t] = (t < ny) ? (tent_int(y2 - (float)i) - tent_int(y1 - (float)i)) : 0.0f;
    } else if (t < 32) {
        int tt = t - 16, j = j_lo + tt;
        sWx[tt] = (tt < nx) ? (tent_int(x2 - (float)j) - tent_int(x1 - (float)j)) : 0.0f;
    }
    __syncthreads();
    const float* fb = feature + ((size_t)b * C + t) * HW;
    float acc = 0.0f;
    for (int ii = 0; ii < ny; ++ii) {
        const float* row = fb + (size_t)(i_lo + ii) * W + j_lo;
        float rowsum = 0.0f;
        for (int jj = 0; jj < nx; ++jj) rowsum = fmaf(sWx[jj], row[jj], rowsum);
        acc = fmaf(sWy[ii], rowsum, acc);
    }
    const float bw = (x2 - x1) * (1.0f / 7.0f), bh = (y2 - y1) * (1.0f / 7.0f);
    const float area = fmaxf(bw * bh, 0.0f);
    out[(size_t)r * C + t] = (area > 0.0f) ? (acc / (49.0f * fmaxf(area, 1e-12f))) : 0.0f;
}

extern "C" void kernel_launch(void* const* d_in, const int* in_sizes, int n_in,
                              void* d_out, int out_size, void* d_ws, size_t ws_size,
                              hipStream_t stream) {
    const float* feature = (const float*)d_in[0];
    const float* rois    = (const float*)d_in[1];
    float* out           = (float*)d_out;

    const size_t need = (size_t)B * HW * C * sizeof(unsigned short);  // 4 MB
    if (ws_size >= need) {
        unsigned short* ft = (unsigned short*)d_ws;
        transpose_kernel<<<B * (HW / 64), 256, 0, stream>>>(feature, ft);
        prroi_main<<<R, 64, 0, stream>>>(ft, rois, out);
    } else {
        prroi_fallback<<<R, 64, 0, stream>>>(feature, rois, out);
    }
}